// Round 10
// baseline (901.780 us; speedup 1.0000x reference)
//
#include <hip/hip_runtime.h>
#include <hip/hip_bf16.h>

typedef __attribute__((ext_vector_type(8))) short short8;
typedef __attribute__((ext_vector_type(4))) float floatx4;

#define IN_DIM  4096
#define OUT_DIM 4096
#define MROWS   16384
#define GSIZE   128

template <int N> struct IC { static constexpr int value = N; };

__device__ __forceinline__ unsigned short f2bf(float f) {
    unsigned int u = __builtin_bit_cast(unsigned int, f);
    u = (u + 0x7fffu + ((u >> 16) & 1u)) >> 16;
    return (unsigned short)u;
}

#define GLD16(gsrc, ldst)                                                     \
    __builtin_amdgcn_global_load_lds(                                         \
        (const __attribute__((address_space(1))) unsigned int*)(const void*)(gsrc), \
        (__attribute__((address_space(3))) unsigned int*)(void*)(ldst),       \
        16, 0, 0)

// ---------------------------------------------------------------- convert x
__global__ void convert_x(const float* __restrict__ x,
                          unsigned short* __restrict__ xb, int n8) {
    int stride = gridDim.x * blockDim.x;
    for (int i = blockIdx.x * blockDim.x + threadIdx.x; i < n8; i += stride) {
        const float4* xf = (const float4*)x;
        float4 f0 = xf[2 * i];
        float4 f1 = xf[2 * i + 1];
        union { unsigned short u[8]; uint4 v; } pk;
        pk.u[0] = f2bf(f0.x); pk.u[1] = f2bf(f0.y);
        pk.u[2] = f2bf(f0.z); pk.u[3] = f2bf(f0.w);
        pk.u[4] = f2bf(f1.x); pk.u[5] = f2bf(f1.y);
        pk.u[6] = f2bf(f1.z); pk.u[7] = f2bf(f1.w);
        ((uint4*)xb)[i] = pk.v;
    }
}

// ---------------------------------------------------------------- decode W
__global__ void decode_w(const int* __restrict__ pw,
                         const float* __restrict__ norms,
                         const float* __restrict__ s1,
                         const float* __restrict__ s2,
                         const float* __restrict__ cent,
                         unsigned short* __restrict__ W) {
    int row  = blockIdx.x * 4 + (threadIdx.x >> 6);
    int lane = threadIdx.x & 63;
    float nrm = norms[row];
    int c0 = pw[(size_t)row * GSIZE + lane];
    int c1 = pw[(size_t)row * GSIZE + lane + 64];
    float e0 = cent[c0] * nrm * s2[lane];
    float e1 = cent[c1] * nrm * s2[lane + 64];
#pragma unroll
    for (int it = 0; it < 7; ++it) {
        float a = e0, b = e1;
        e0 = a + b;
        e1 = a - b;
    }
    const float inv = 0.08838834764831845f; // 1/sqrt(128)
    int o = row >> 5, g = row & 31;
    unsigned short* wr = W + (size_t)o * IN_DIM + g * GSIZE;
    wr[lane]      = f2bf(e0 * inv * s1[lane]);
    wr[lane + 64] = f2bf(e1 * inv * s1[lane + 64]);
}

// ---------------------------------------------------------------- GEMM
// 256x256 tile, BK=64, **4 waves** (2x2), wave-tile 128x128.
// Per-CU LDS reads drop 192->128 per K-tile vs the 8-wave layout, and the
// whole K-tile needs ONE barrier. 1 wave/SIMD (full 512-reg budget, pinned
// by amdgpu_waves_per_eu(1,1)): acc 8x8 (256 regs) + frags 32xshort8 (128).
//
// Per K-tile j (BF=j&1), per wave:
//   LD ks1(j) from BF        (16 ds_read_b128, drain under MFMA ks0)
//   MFMA ks0(j)              (64 MFMA; operands read at end of body(j-1))
//   vmcnt(0)  [cold ~2600cy] (tile j+1 stage loads, issued body(j-1))
//   lgkmcnt(0)[cold ~1240cy] (my ks1(j)+older ds_reads complete)
//   BARRIER                  (globalizes WAR-on-BF and RAW-on-tile-j+1)
//   STG(j+2 -> BF)           (16 global_load_lds per thread)
//   LD ks0(j+1) from BF^1    (16 reads, drain under MFMA ks1)
//   MFMA ks1(j)
__global__ __launch_bounds__(256)
__attribute__((amdgpu_waves_per_eu(1, 1)))
void gemm_bf16(const unsigned short* __restrict__ Xg,
               const unsigned short* __restrict__ Wg,
               const float* __restrict__ bias,
               float* __restrict__ out) {
    __shared__ unsigned short As[2][256][64];
    __shared__ unsigned short Bs[2][256][64];

    // bijective XCD swizzle (1024 blocks % 8 == 0); consecutive ids share mt
    int id = (blockIdx.x & 7) * 128 + (blockIdx.x >> 3);
    int mt = id >> 4, nt = id & 15;
    int m0 = mt * 256, n0 = nt * 256;

    int tid  = threadIdx.x;
    int lane = tid & 63;
    int wid  = tid >> 6;
    int wm = wid >> 1, wn = wid & 1;   // wave tile: rows wm*128+, cols wn*128+

    // staging: thread covers chunk cp0 of rows sr0+32*i, i=0..7 (per matrix)
    int sr0 = tid >> 3;        // 0..31
    int cp0 = tid & 7;         // physical 16B-chunk position
    int sg0 = cp0 ^ (sr0 & 7); // global chunk (inverse swizzle; +32k keeps &7)

#define STG_TILE(bufc, j) do {                                                \
    _Pragma("unroll") for (int i = 0; i < 8; ++i) {                           \
        int _r = sr0 + 32 * i;                                                \
        GLD16(Xg + (size_t)(m0 + _r) * IN_DIM + (size_t)(j)*64 + sg0*8,       \
              &As[bufc][_r][cp0 * 8]);                                        \
        GLD16(Wg + (size_t)(n0 + _r) * IN_DIM + (size_t)(j)*64 + sg0*8,       \
              &Bs[bufc][_r][cp0 * 8]);                                        \
    }                                                                         \
  } while (0)

    int rl = lane & 15, kc = lane >> 4;
    short8 a_[8][2], b_[8][2];
    floatx4 acc[8][8] = {};

#define LD_A(BFc, m, ks) do {                                                 \
    int row_ = wm * 128 + (m)*16 + rl;                                        \
    a_[m][ks] = *(const short8*)&As[BFc][row_][((((ks)*4 + kc) ^ (rl & 7)) << 3)]; \
  } while (0)
#define LD_B(BFc, n, ks) do {                                                 \
    int row_ = wn * 128 + (n)*16 + rl;                                        \
    b_[n][ks] = *(const short8*)&Bs[BFc][row_][((((ks)*4 + kc) ^ (rl & 7)) << 3)]; \
  } while (0)
#define LD_SLICE(BFc, ks) do {                                                \
    LD_B(BFc, 0, ks); LD_B(BFc, 1, ks); LD_B(BFc, 2, ks); LD_B(BFc, 3, ks);   \
    LD_B(BFc, 4, ks); LD_B(BFc, 5, ks); LD_B(BFc, 6, ks); LD_B(BFc, 7, ks);   \
    LD_A(BFc, 0, ks); LD_A(BFc, 1, ks); LD_A(BFc, 2, ks); LD_A(BFc, 3, ks);   \
    LD_A(BFc, 4, ks); LD_A(BFc, 5, ks); LD_A(BFc, 6, ks); LD_A(BFc, 7, ks);   \
  } while (0)

#define MFMA_KS(ks) do {                                                      \
    _Pragma("unroll") for (int m = 0; m < 8; ++m) {                           \
      _Pragma("unroll") for (int n = 0; n < 8; ++n)                           \
        acc[m][n] = __builtin_amdgcn_mfma_f32_16x16x32_bf16(                  \
            a_[m][ks], b_[n][ks], acc[m][n], 0, 0, 0);                        \
    }                                                                         \
  } while (0)

    // ---- prologue: stage tiles 0,1 (32 loads/thread); certify tile0
    STG_TILE(0, 0);
    STG_TILE(1, 1);
    asm volatile("s_waitcnt vmcnt(16)" ::: "memory");  // tile0 resident
    __builtin_amdgcn_s_barrier();
    LD_SLICE(0, 0);

    // MODE: 2 = steady; 1 = j=62 (no STG); 0 = j=63 (tail)
    auto body = [&](int j, auto bfc, auto modec) {
        constexpr int BF   = decltype(bfc)::value;
        constexpr int MODE = decltype(modec)::value;
        LD_SLICE(BF, 1);                              // ks1(j), drain under MFMA
        MFMA_KS(0);                                   // counted lgkm by compiler
        if constexpr (MODE >= 1) {
            asm volatile("s_waitcnt vmcnt(0)" ::: "memory");   // tile j+1 landed
            asm volatile("s_waitcnt lgkmcnt(0)" ::: "memory"); // my BF reads done
            __builtin_amdgcn_s_barrier();                      // single barrier
            if constexpr (MODE == 2) STG_TILE(BF, j + 2);
            LD_SLICE(BF ^ 1, 0);                               // ks0(j+1)
        }
        MFMA_KS(1);
    };

    for (int j = 0; j < 62; j += 2) {
        body(j,     IC<0>{}, IC<2>{});
        body(j + 1, IC<1>{}, IC<2>{});
    }
    body(62, IC<0>{}, IC<1>{});
    body(63, IC<1>{}, IC<0>{});

    // ---- epilogue: C/D layout col = lane&15, row = (lane>>4)*4 + i
    int q = lane >> 4;
#pragma unroll
    for (int n = 0; n < 8; ++n) {
        int col = n0 + wn * 128 + n * 16 + rl;
        float bv = bias[col];
#pragma unroll
        for (int m = 0; m < 8; ++m) {
#pragma unroll
            for (int i = 0; i < 4; ++i) {
                int row = m0 + wm * 128 + m * 16 + q * 4 + i;
                out[(size_t)row * OUT_DIM + col] = acc[m][n][i] + bv;
            }
        }
    }
#undef STG_TILE
#undef LD_A
#undef LD_B
#undef LD_SLICE
#undef MFMA_KS
}

// ---------------------------------------------------------------- launch
extern "C" void kernel_launch(void* const* d_in, const int* in_sizes, int n_in,
                              void* d_out, int out_size, void* d_ws, size_t ws_size,
                              hipStream_t stream) {
    const float* x     = (const float*)d_in[0];
    const int*   pw    = (const int*)d_in[1];
    const float* norms = (const float*)d_in[2];
    const float* s1    = (const float*)d_in[3];
    const float* s2    = (const float*)d_in[4];
    const float* cent  = (const float*)d_in[5];
    const float* bias  = (const float*)d_in[6];
    float* out = (float*)d_out;

    size_t needX = (size_t)MROWS * IN_DIM * 2;    // 128 MB
    size_t needW = (size_t)OUT_DIM * IN_DIM * 2;  //  32 MB
    if (ws_size < needX + needW) return;

    unsigned short* Xb = (unsigned short*)d_ws;
    unsigned short* Wb = (unsigned short*)((char*)d_ws + needX);

    convert_x<<<2048, 256, 0, stream>>>(x, Xb, MROWS * IN_DIM / 8);
    decode_w<<<(OUT_DIM * 32) / 4, 256, 0, stream>>>(pw, norms, s1, s2, cent, Wb);
    gemm_bf16<<<(MROWS / 256) * (OUT_DIM / 256), 256, 0, stream>>>(Xb, Wb, bias, out);
}

// Round 11
// 714.022 us; speedup vs baseline: 1.2630x; 1.2630x over previous
//
#include <hip/hip_runtime.h>
#include <hip/hip_bf16.h>

typedef __attribute__((ext_vector_type(8))) short short8;
typedef __attribute__((ext_vector_type(4))) float floatx4;

#define IN_DIM  4096
#define OUT_DIM 4096
#define MROWS   16384
#define GSIZE   128

template <int N> struct IC { static constexpr int value = N; };

__device__ __forceinline__ unsigned short f2bf(float f) {
    unsigned int u = __builtin_bit_cast(unsigned int, f);
    u = (u + 0x7fffu + ((u >> 16) & 1u)) >> 16;
    return (unsigned short)u;
}

#define GLD16(gsrc, ldst)                                                     \
    __builtin_amdgcn_global_load_lds(                                         \
        (const __attribute__((address_space(1))) unsigned int*)(const void*)(gsrc), \
        (__attribute__((address_space(3))) unsigned int*)(void*)(ldst),       \
        16, 0, 0)

// ---------------------------------------------------------------- convert x
__global__ void convert_x(const float* __restrict__ x,
                          unsigned short* __restrict__ xb, int n8) {
    int stride = gridDim.x * blockDim.x;
    for (int i = blockIdx.x * blockDim.x + threadIdx.x; i < n8; i += stride) {
        const float4* xf = (const float4*)x;
        float4 f0 = xf[2 * i];
        float4 f1 = xf[2 * i + 1];
        union { unsigned short u[8]; uint4 v; } pk;
        pk.u[0] = f2bf(f0.x); pk.u[1] = f2bf(f0.y);
        pk.u[2] = f2bf(f0.z); pk.u[3] = f2bf(f0.w);
        pk.u[4] = f2bf(f1.x); pk.u[5] = f2bf(f1.y);
        pk.u[6] = f2bf(f1.z); pk.u[7] = f2bf(f1.w);
        ((uint4*)xb)[i] = pk.v;
    }
}

// ---------------------------------------------------------------- decode W
__global__ void decode_w(const int* __restrict__ pw,
                         const float* __restrict__ norms,
                         const float* __restrict__ s1,
                         const float* __restrict__ s2,
                         const float* __restrict__ cent,
                         unsigned short* __restrict__ W) {
    int row  = blockIdx.x * 4 + (threadIdx.x >> 6);
    int lane = threadIdx.x & 63;
    float nrm = norms[row];
    int c0 = pw[(size_t)row * GSIZE + lane];
    int c1 = pw[(size_t)row * GSIZE + lane + 64];
    float e0 = cent[c0] * nrm * s2[lane];
    float e1 = cent[c1] * nrm * s2[lane + 64];
#pragma unroll
    for (int it = 0; it < 7; ++it) {
        float a = e0, b = e1;
        e0 = a + b;
        e1 = a - b;
    }
    const float inv = 0.08838834764831845f; // 1/sqrt(128)
    int o = row >> 5, g = row & 31;
    unsigned short* wr = W + (size_t)o * IN_DIM + g * GSIZE;
    wr[lane]      = f2bf(e0 * inv * s1[lane]);
    wr[lane + 64] = f2bf(e1 * inv * s1[lane + 64]);
}

// ---------------------------------------------------------------- GEMM
// 256x256 tile, BK=64, 8 waves (2M x 4N). MINIMAL-PROTOCOL K-tile:
// all 24 ds_reads + all 32 MFMAs emitted with NO manual waits or pins --
// the compiler inserts exact per-MFMA counted lgkmcnt, so MFMA issue
// starts ~120cy into the tile and overlaps the LDS drain (R6's per-phase
// lgkmcnt(0) forced a full-burst drain before EVERY MFMA cluster -- that
// was the serializer). Hazard certs once per K-tile:
//   lgkmcnt(0)  [cold: reads had the whole tile]  -> barrier #1
//     (WAR: every wave's reads of BF complete before STG overwrites BF)
//   STG(j+2 -> BF)  [8 global_load_lds]
//   vmcnt(8)    [cold: waits tile j+1's loads, issued one tile ago]
//   -> barrier #2  (RAW: tile j+1 readable by all)
__global__ __launch_bounds__(512, 2)
void gemm_bf16(const unsigned short* __restrict__ Xg,
               const unsigned short* __restrict__ Wg,
               const float* __restrict__ bias,
               float* __restrict__ out) {
    __shared__ unsigned short As[2][256][64];
    __shared__ unsigned short Bs[2][256][64];

    // bijective XCD swizzle (1024 blocks % 8 == 0); consecutive ids share mt
    int id = (blockIdx.x & 7) * 128 + (blockIdx.x >> 3);
    int mt = id >> 4, nt = id & 15;
    int m0 = mt * 256, n0 = nt * 256;

    int tid  = threadIdx.x;
    int lane = tid & 63;
    int wid  = tid >> 6;
    int wm = wid >> 2, wn = wid & 3;   // wave tile: rows wm*128+, cols wn*64+

    // staging: thread handles 16B phys chunk cp0 of rows sr0 / sr0+64
    int sr0 = tid >> 3;        // 0..63
    int cp0 = tid & 7;         // physical chunk position
    int sg0 = cp0 ^ (sr0 & 7); // global chunk (inverse swizzle)

#define STG_A(bufc, h, j) do {                                                \
    const unsigned short* _s =                                                \
        Xg + (size_t)(m0 + (h)*128 + sr0) * IN_DIM + (size_t)(j)*64 + sg0*8;  \
    GLD16(_s,                &As[bufc][(h)*128 + sr0][cp0 * 8]);              \
    GLD16(_s + 64 * IN_DIM,  &As[bufc][(h)*128 + sr0 + 64][cp0 * 8]);         \
  } while (0)
#define STG_B(bufc, h, j) do {                                                \
    const unsigned short* _s =                                                \
        Wg + (size_t)(n0 + (h)*128 + sr0) * IN_DIM + (size_t)(j)*64 + sg0*8;  \
    GLD16(_s,                &Bs[bufc][(h)*128 + sr0][cp0 * 8]);              \
    GLD16(_s + 64 * IN_DIM,  &Bs[bufc][(h)*128 + sr0 + 64][cp0 * 8]);         \
  } while (0)
#define STG_TILE(bufc, j) do {                                                \
    STG_B(bufc, 0, j); STG_B(bufc, 1, j);                                     \
    STG_A(bufc, 0, j); STG_A(bufc, 1, j);                                     \
  } while (0)

    int rl = lane & 15, kc = lane >> 4;
    short8 a_[8][2], b_[4][2];
    floatx4 acc[8][4] = {};

#define LD_A(BFc, m, ks) do {                                                 \
    int row_ = wm * 128 + (m)*16 + rl;                                        \
    a_[m][ks] = *(const short8*)&As[BFc][row_][((((ks)*4 + kc) ^ (row_ & 7)) << 3)]; \
  } while (0)
#define LD_B(BFc, n, ks) do {                                                 \
    int row_ = wn * 64 + (n)*16 + rl;                                         \
    b_[n][ks] = *(const short8*)&Bs[BFc][row_][((((ks)*4 + kc) ^ (row_ & 7)) << 3)]; \
  } while (0)

    // ---- prologue: stage tiles 0,1; certify tile0
    STG_TILE(0, 0);
    STG_TILE(1, 1);
    asm volatile("s_waitcnt vmcnt(8)" ::: "memory");  // tile0 resident
    __builtin_amdgcn_s_barrier();

    // MODE: 2 = steady; 1 = j=62 (no STG, vmcnt(0)); 0 = j=63 (tail)
    auto body = [&](int j, auto bfc, auto modec) {
        constexpr int BF   = decltype(bfc)::value;
        constexpr int MODE = decltype(modec)::value;
        // ---- all reads of tile j (B first: earliest MFMA operands)
        LD_B(BF, 0, 0); LD_B(BF, 0, 1); LD_B(BF, 1, 0); LD_B(BF, 1, 1);
        LD_B(BF, 2, 0); LD_B(BF, 2, 1); LD_B(BF, 3, 0); LD_B(BF, 3, 1);
        LD_A(BF, 0, 0); LD_A(BF, 0, 1); LD_A(BF, 1, 0); LD_A(BF, 1, 1);
        LD_A(BF, 2, 0); LD_A(BF, 2, 1); LD_A(BF, 3, 0); LD_A(BF, 3, 1);
        LD_A(BF, 4, 0); LD_A(BF, 4, 1); LD_A(BF, 5, 0); LD_A(BF, 5, 1);
        LD_A(BF, 6, 0); LD_A(BF, 6, 1); LD_A(BF, 7, 0); LD_A(BF, 7, 1);
        // ---- all 32 MFMAs; compiler inserts exact counted lgkmcnt per use
        __builtin_amdgcn_s_setprio(1);
#pragma unroll
        for (int m = 0; m < 8; ++m) {
#pragma unroll
            for (int n = 0; n < 4; ++n) {
#pragma unroll
                for (int ks = 0; ks < 2; ++ks)
                    acc[m][n] = __builtin_amdgcn_mfma_f32_16x16x32_bf16(
                        a_[m][ks], b_[n][ks], acc[m][n], 0, 0, 0);
            }
        }
        __builtin_amdgcn_s_setprio(0);
        // ---- once-per-tile hazard certs
        if constexpr (MODE >= 1) {
            asm volatile("s_waitcnt lgkmcnt(0)" ::: "memory"); // my BF reads done
            __builtin_amdgcn_s_barrier();                      // #1: BF free
            if constexpr (MODE == 2) {
                STG_TILE(BF, j + 2);
                asm volatile("s_waitcnt vmcnt(8)" ::: "memory"); // j+1 landed
            } else {
                asm volatile("s_waitcnt vmcnt(0)" ::: "memory"); // j+1 landed
            }
            __builtin_amdgcn_s_barrier();                      // #2: j+1 readable
        }
    };

    for (int j = 0; j < 62; j += 2) {
        body(j,     IC<0>{}, IC<2>{});
        body(j + 1, IC<1>{}, IC<2>{});
    }
    body(62, IC<0>{}, IC<1>{});
    body(63, IC<1>{}, IC<0>{});

    // ---- epilogue: C/D layout col = lane&15, row = (lane>>4)*4 + i
    int q = lane >> 4;
#pragma unroll
    for (int n = 0; n < 4; ++n) {
        int col = n0 + wn * 64 + n * 16 + rl;
        float bv = bias[col];
#pragma unroll
        for (int m = 0; m < 8; ++m) {
#pragma unroll
            for (int i = 0; i < 4; ++i) {
                int row = m0 + wm * 128 + m * 16 + q * 4 + i;
                out[(size_t)row * OUT_DIM + col] = acc[m][n][i] + bv;
            }
        }
    }
#undef STG_A
#undef STG_B
#undef STG_TILE
#undef LD_A
#undef LD_B
}

// ---------------------------------------------------------------- launch
extern "C" void kernel_launch(void* const* d_in, const int* in_sizes, int n_in,
                              void* d_out, int out_size, void* d_ws, size_t ws_size,
                              hipStream_t stream) {
    const float* x     = (const float*)d_in[0];
    const int*   pw    = (const int*)d_in[1];
    const float* norms = (const float*)d_in[2];
    const float* s1    = (const float*)d_in[3];
    const float* s2    = (const float*)d_in[4];
    const float* cent  = (const float*)d_in[5];
    const float* bias  = (const float*)d_in[6];
    float* out = (float*)d_out;

    size_t needX = (size_t)MROWS * IN_DIM * 2;    // 128 MB
    size_t needW = (size_t)OUT_DIM * IN_DIM * 2;  //  32 MB
    if (ws_size < needX + needW) return;

    unsigned short* Xb = (unsigned short*)d_ws;
    unsigned short* Wb = (unsigned short*)((char*)d_ws + needX);

    convert_x<<<2048, 256, 0, stream>>>(x, Xb, MROWS * IN_DIM / 8);
    decode_w<<<(OUT_DIM * 32) / 4, 256, 0, stream>>>(pw, norms, s1, s2, cent, Wb);
    gemm_bf16<<<(MROWS / 256) * (OUT_DIM / 256), 512, 0, stream>>>(Xb, Wb, bias, out);
}

// Round 12
// 689.732 us; speedup vs baseline: 1.3074x; 1.0352x over previous
//
#include <hip/hip_runtime.h>
#include <hip/hip_bf16.h>

typedef __attribute__((ext_vector_type(8))) short short8;
typedef __attribute__((ext_vector_type(16))) float floatx16;

#define IN_DIM  4096
#define OUT_DIM 4096
#define MROWS   16384
#define GSIZE   128

template <int N> struct IC { static constexpr int value = N; };

__device__ __forceinline__ unsigned short f2bf(float f) {
    unsigned int u = __builtin_bit_cast(unsigned int, f);
    u = (u + 0x7fffu + ((u >> 16) & 1u)) >> 16;
    return (unsigned short)u;
}

#define GLD16(gsrc, ldst)                                                     \
    __builtin_amdgcn_global_load_lds(                                         \
        (const __attribute__((address_space(1))) unsigned int*)(const void*)(gsrc), \
        (__attribute__((address_space(3))) unsigned int*)(void*)(ldst),       \
        16, 0, 0)

// ---------------------------------------------------------------- convert x
__global__ void convert_x(const float* __restrict__ x,
                          unsigned short* __restrict__ xb, int n8) {
    int stride = gridDim.x * blockDim.x;
    for (int i = blockIdx.x * blockDim.x + threadIdx.x; i < n8; i += stride) {
        const float4* xf = (const float4*)x;
        float4 f0 = xf[2 * i];
        float4 f1 = xf[2 * i + 1];
        union { unsigned short u[8]; uint4 v; } pk;
        pk.u[0] = f2bf(f0.x); pk.u[1] = f2bf(f0.y);
        pk.u[2] = f2bf(f0.z); pk.u[3] = f2bf(f0.w);
        pk.u[4] = f2bf(f1.x); pk.u[5] = f2bf(f1.y);
        pk.u[6] = f2bf(f1.z); pk.u[7] = f2bf(f1.w);
        ((uint4*)xb)[i] = pk.v;
    }
}

// ---------------------------------------------------------------- decode W
__global__ void decode_w(const int* __restrict__ pw,
                         const float* __restrict__ norms,
                         const float* __restrict__ s1,
                         const float* __restrict__ s2,
                         const float* __restrict__ cent,
                         unsigned short* __restrict__ W) {
    int row  = blockIdx.x * 4 + (threadIdx.x >> 6);
    int lane = threadIdx.x & 63;
    float nrm = norms[row];
    int c0 = pw[(size_t)row * GSIZE + lane];
    int c1 = pw[(size_t)row * GSIZE + lane + 64];
    float e0 = cent[c0] * nrm * s2[lane];
    float e1 = cent[c1] * nrm * s2[lane + 64];
#pragma unroll
    for (int it = 0; it < 7; ++it) {
        float a = e0, b = e1;
        e0 = a + b;
        e1 = a - b;
    }
    const float inv = 0.08838834764831845f; // 1/sqrt(128)
    int o = row >> 5, g = row & 31;
    unsigned short* wr = W + (size_t)o * IN_DIM + g * GSIZE;
    wr[lane]      = f2bf(e0 * inv * s1[lane]);
    wr[lane + 64] = f2bf(e1 * inv * s1[lane + 64]);
}

// ---------------------------------------------------------------- GEMM
// R6's proven 8-phase schedule, MFMA shape switched to 32x32x16 bf16
// (2495 vs 2075 TF ubench: -17% matrix-pipe time; half the MFMA instrs).
// 256x256 tile, BK=64, 8 waves (2M x 4N), wave-tile 128x64.
// Per wave: A frags mb0-3 (32 rows each) x ks0-3 (K=16); B frags nb0-1.
// Reads: 24 ds_read_b128/wave/K-tile (same as 16x16 path).
// A operand: lane l -> row l&31, k-half l>>5, 8 k-contig bf16 (16B).
// C/D: col = lane&31, row = (reg&3)+8*(reg>>2)+4*(lane>>5)  [m74/m101].
//
// Phases per K-tile j (BF=j&1):
//  p0: read B nb0 + A mb0,1 (12); stage A1(j+1)->BF^1; lgkm(8); bar;
//      lgkm(0); MFMA mb01 x nb0 (8); bar
//  p1: read B nb1 (4); stage A0(j+2)->BF; bar; lgkm(0); MFMA mb01 x nb1; bar
//  p2: read A mb2,3 (8); stage B0(j+2)->BF; bar; lgkm(0); MFMA mb23 x nb0; bar
//  p3: stage B1(j+2)->BF; vmcnt(6) [tile j+1 resident]; bar; MFMA mb23 x nb1; bar
// Region certs identical to R6 (A0 = mb01-rows read p0 only; A1 = mb23 read
// p2 only; B fully read by p1 end-bar).
__global__ __launch_bounds__(512, 2)
void gemm_bf16(const unsigned short* __restrict__ Xg,
               const unsigned short* __restrict__ Wg,
               const float* __restrict__ bias,
               float* __restrict__ out) {
    __shared__ unsigned short As[2][256][64];
    __shared__ unsigned short Bs[2][256][64];

    // bijective XCD swizzle (1024 blocks % 8 == 0); consecutive ids share mt
    int id = (blockIdx.x & 7) * 128 + (blockIdx.x >> 3);
    int mt = id >> 4, nt = id & 15;
    int m0 = mt * 256, n0 = nt * 256;

    int tid  = threadIdx.x;
    int lane = tid & 63;
    int wid  = tid >> 6;
    int wm = wid >> 2, wn = wid & 3;   // wave tile: rows wm*128+, cols wn*64+

    // staging: thread handles 16B phys chunk cp0 of rows sr0 / sr0+64(+128)
    int sr0 = tid >> 3;        // 0..63
    int cp0 = tid & 7;         // physical chunk position
    int sg0 = cp0 ^ (sr0 & 7); // global chunk (inverse swizzle)

// A halves interleaved: h=0 -> rows [0,64)u[128,192) (mb 0,1 of both wm),
//                       h=1 -> rows [64,128)u[192,256) (mb 2,3)
#define STG_AH(bufc, h, j) do {                                               \
    const unsigned short* _s =                                                \
        Xg + (size_t)(m0 + (h)*64 + sr0) * IN_DIM + (size_t)(j)*64 + sg0*8;   \
    GLD16(_s,                 &As[bufc][(h)*64 + sr0][cp0 * 8]);              \
    GLD16(_s + 128 * IN_DIM,  &As[bufc][128 + (h)*64 + sr0][cp0 * 8]);        \
  } while (0)
// B halves contiguous: h=0 -> rows [0,128), h=1 -> rows [128,256)
#define STG_BH(bufc, h, j) do {                                               \
    const unsigned short* _s =                                                \
        Wg + (size_t)(n0 + (h)*128 + sr0) * IN_DIM + (size_t)(j)*64 + sg0*8;  \
    GLD16(_s,                &Bs[bufc][(h)*128 + sr0][cp0 * 8]);              \
    GLD16(_s + 64 * IN_DIM,  &Bs[bufc][(h)*128 + sr0 + 64][cp0 * 8]);         \
  } while (0)

    int rl = lane & 31;        // row/col within 32-block
    int hi = lane >> 5;        // k-half selector
    short8 a_[4][4], b_[2][4]; // [mb][ks], [nb][ks]
    floatx16 acc[4][2] = {};   // [mb][nb]

    // chunk c = ks*2 + hi; phys = c ^ (row&7); row&7 == rl&7 (blocks are
    // multiples of 32 rows)
#define LD_A(BFc, mb, ks) do {                                                \
    int row_ = wm * 128 + (mb)*32 + rl;                                       \
    a_[mb][ks] = *(const short8*)                                             \
        &As[BFc][row_][((((ks)*2 + hi) ^ (rl & 7)) << 3)];                    \
  } while (0)
#define LD_B(BFc, nb, ks) do {                                                \
    int row_ = wn * 64 + (nb)*32 + rl;                                        \
    b_[nb][ks] = *(const short8*)                                             \
        &Bs[BFc][row_][((((ks)*2 + hi) ^ (rl & 7)) << 3)];                    \
  } while (0)

#define MFMA_Q(mh, nb) do {                                                   \
    __builtin_amdgcn_s_setprio(1);                                            \
    _Pragma("unroll") for (int ks = 0; ks < 4; ++ks) {                        \
      _Pragma("unroll") for (int mm = 0; mm < 2; ++mm)                        \
        acc[2*(mh)+mm][nb] = __builtin_amdgcn_mfma_f32_32x32x16_bf16(         \
            a_[2*(mh)+mm][ks], b_[nb][ks], acc[2*(mh)+mm][nb], 0, 0, 0);      \
    }                                                                         \
    __builtin_amdgcn_s_setprio(0);                                            \
  } while (0)

    // ---- prologue: tile0 full (8 loads); A0,B0,B1 of tile1 (6 loads)
    STG_BH(0, 0, 0); STG_BH(0, 1, 0); STG_AH(0, 0, 0); STG_AH(0, 1, 0);
    STG_AH(1, 0, 1); STG_BH(1, 0, 1); STG_BH(1, 1, 1);
    asm volatile("s_waitcnt vmcnt(6)" ::: "memory");  // tile0 resident
    __builtin_amdgcn_s_barrier();

    // MODE: 2 = steady; 1 = j=62 (stage A1(63) only, vmcnt(0)); 0 = j=63
    auto body = [&](int j, auto bfc, auto modec) {
        constexpr int BF   = decltype(bfc)::value;
        constexpr int MODE = decltype(modec)::value;
        // ---- p0: B nb0 + A mb0,1 (12 reads); stage A1(j+1)
        LD_B(BF, 0, 0); LD_B(BF, 0, 1); LD_B(BF, 0, 2); LD_B(BF, 0, 3);
        LD_A(BF, 0, 0); LD_A(BF, 0, 1); LD_A(BF, 0, 2); LD_A(BF, 0, 3);
        LD_A(BF, 1, 0); LD_A(BF, 1, 1); LD_A(BF, 1, 2); LD_A(BF, 1, 3);
        if constexpr (MODE >= 1) STG_AH(BF ^ 1, 1, j + 1);
        asm volatile("s_waitcnt lgkmcnt(8)" ::: "memory");
        __builtin_amdgcn_s_barrier();
        asm volatile("s_waitcnt lgkmcnt(0)" ::: "memory");
        MFMA_Q(0, 0);
        __builtin_amdgcn_s_barrier();
        // ---- p1: B nb1 (4 reads); stage A0(j+2)
        LD_B(BF, 1, 0); LD_B(BF, 1, 1); LD_B(BF, 1, 2); LD_B(BF, 1, 3);
        if constexpr (MODE == 2) STG_AH(BF, 0, j + 2);
        __builtin_amdgcn_s_barrier();
        asm volatile("s_waitcnt lgkmcnt(0)" ::: "memory");
        MFMA_Q(0, 1);
        __builtin_amdgcn_s_barrier();
        // ---- p2: A mb2,3 (8 reads); stage B0(j+2)
        LD_A(BF, 2, 0); LD_A(BF, 2, 1); LD_A(BF, 2, 2); LD_A(BF, 2, 3);
        LD_A(BF, 3, 0); LD_A(BF, 3, 1); LD_A(BF, 3, 2); LD_A(BF, 3, 3);
        if constexpr (MODE == 2) STG_BH(BF, 0, j + 2);
        __builtin_amdgcn_s_barrier();
        asm volatile("s_waitcnt lgkmcnt(0)" ::: "memory");
        MFMA_Q(1, 0);
        __builtin_amdgcn_s_barrier();
        // ---- p3: stage B1(j+2); counted vmcnt certifies tile j+1
        if constexpr (MODE == 2) {
            STG_BH(BF, 1, j + 2);
            asm volatile("s_waitcnt vmcnt(6)" ::: "memory");
        } else if constexpr (MODE == 1) {
            asm volatile("s_waitcnt vmcnt(0)" ::: "memory");
        }
        __builtin_amdgcn_s_barrier();
        MFMA_Q(1, 1);
        __builtin_amdgcn_s_barrier();
    };

    for (int j = 0; j < 62; j += 2) {
        body(j,     IC<0>{}, IC<2>{});
        body(j + 1, IC<1>{}, IC<2>{});
    }
    body(62, IC<0>{}, IC<1>{});
    body(63, IC<1>{}, IC<0>{});

    // ---- epilogue: 32x32 C/D: col = lane&31, row = (reg&3)+8*(reg>>2)+4*hi
#pragma unroll
    for (int nb = 0; nb < 2; ++nb) {
        int col = n0 + wn * 64 + nb * 32 + rl;
        float bv = bias[col];
#pragma unroll
        for (int mb = 0; mb < 4; ++mb) {
#pragma unroll
            for (int r = 0; r < 16; ++r) {
                int row = m0 + wm * 128 + mb * 32 + (r & 3) + 8 * (r >> 2) + 4 * hi;
                out[(size_t)row * OUT_DIM + col] = acc[mb][nb][r] + bv;
            }
        }
    }
#undef STG_AH
#undef STG_BH
#undef LD_A
#undef LD_B
#undef MFMA_Q
}

// ---------------------------------------------------------------- launch
extern "C" void kernel_launch(void* const* d_in, const int* in_sizes, int n_in,
                              void* d_out, int out_size, void* d_ws, size_t ws_size,
                              hipStream_t stream) {
    const float* x     = (const float*)d_in[0];
    const int*   pw    = (const int*)d_in[1];
    const float* norms = (const float*)d_in[2];
    const float* s1    = (const float*)d_in[3];
    const float* s2    = (const float*)d_in[4];
    const float* cent  = (const float*)d_in[5];
    const float* bias  = (const float*)d_in[6];
    float* out = (float*)d_out;

    size_t needX = (size_t)MROWS * IN_DIM * 2;    // 128 MB
    size_t needW = (size_t)OUT_DIM * IN_DIM * 2;  //  32 MB
    if (ws_size < needX + needW) return;

    unsigned short* Xb = (unsigned short*)d_ws;
    unsigned short* Wb = (unsigned short*)((char*)d_ws + needX);

    convert_x<<<2048, 256, 0, stream>>>(x, Xb, MROWS * IN_DIM / 8);
    decode_w<<<(OUT_DIM * 32) / 4, 256, 0, stream>>>(pw, norms, s1, s2, cent, Wb);
    gemm_bf16<<<(MROWS / 256) * (OUT_DIM / 256), 512, 0, stream>>>(Xb, Wb, bias, out);
}